// Round 8
// baseline (196.163 us; speedup 1.0000x reference)
//
#include <hip/hip_runtime.h>
#include <hip/hip_bf16.h>

// Causal linear attention (Performer ReLU kernel) via chunked MFMA (bf16).
// B=2 L=4096 H=8 D=64 M=256 fp32 in/out. Chunk T=128, C=32, NBH=16.
// R8: 3-kernel pipeline.
//  prep: k->kbf (bf16, RATIO folded), V->VTg (bf16 [bh][c][d][t]), proj->Pbf.
//  scan: fused phase1+phase2. Block = (mq 8, bh 16, dh 2); loops 32 chunks
//        keeping running S-prefix IN MFMA ACCUMULATORS (exclusive: store acc
//        before accumulating chunk c). Double-buffered KpT -> 1 barrier/chunk.
//        Z prefix in wave0 registers. fp32 prefix precision.
//  phase3: R6-proven (512,2) structure; loads P/K/V frags from Pbf/kbf/VTg
//        (no VT staging, no cvt VALU). LDS 53.2 KB.
// C/D layout (m89): col = lane&15, row = quad*4 + reg.
// __launch_bounds__: (512,2) proven no-spill at 88 VGPR (R5/R6).
// ws: S bf16 16.8M | Z fp32 0.5M | kbf 8.4M | VTg 8.4M | Pbf 32K ~= 34.1 MB
// (R7 ran its big path => ws_size >= 50.9 MB, so this fits).

#define B_   2
#define L_   4096
#define H_   8
#define D_   64
#define M_   256
#define T_   128
#define C_   (L_ / T_)   // 32
#define NBH  (B_ * H_)   // 16
#define RATIO 0.0625f    // 1/sqrt(256) == 2^-4, exact fold into k/q staging
#define STAB  0.001f
#define SVT  136         // KpL/Am/KpT row stride (272B, 16B-aligned)
#define SQS  72          // Qp stage row stride

typedef __attribute__((ext_vector_type(8))) short short8;
typedef __attribute__((ext_vector_type(4))) float floatx4;

#define MFMA16(a, b, c) __builtin_amdgcn_mfma_f32_16x16x32_bf16(a, b, c, 0, 0, 0)

__device__ inline unsigned short f2bf(float x) {
    union { float f; unsigned u; } v; v.f = x;
    unsigned r = v.u + 0x7FFF + ((v.u >> 16) & 1);
    return (unsigned short)(r >> 16);
}
__device__ inline unsigned pack2bf(float a, float b) {
    __hip_bfloat162 h = __float22bfloat162_rn(make_float2(a, b));
    unsigned u; __builtin_memcpy(&u, &h, 4);
    return u;
}
// q staging with RATIO pre-fold (exact: 2^-4 scales exponent only)
__device__ inline short8 ldg8_bfs(const float* p) {
    float4 a = *(const float4*)p;
    float4 b = *(const float4*)(p + 4);
    short8 r;
    r[0] = (short)f2bf(a.x * RATIO); r[1] = (short)f2bf(a.y * RATIO);
    r[2] = (short)f2bf(a.z * RATIO); r[3] = (short)f2bf(a.w * RATIO);
    r[4] = (short)f2bf(b.x * RATIO); r[5] = (short)f2bf(b.y * RATIO);
    r[6] = (short)f2bf(b.z * RATIO); r[7] = (short)f2bf(b.w * RATIO);
    return r;
}

// ---------------- prep: kbf, VTg, Pbf ----------------
__global__ __launch_bounds__(256, 2)
void prep_kernel(const float* __restrict__ key, const float* __restrict__ val,
                 const float* __restrict__ proj,
                 unsigned short* __restrict__ kbf, unsigned short* __restrict__ VTg,
                 unsigned short* __restrict__ Pbf) {
    const int c = blockIdx.x, bh = blockIdx.y;
    const int b = bh / H_, h = bh % H_;
    const int tid = threadIdx.x;
    __shared__ __align__(16) unsigned short VT[64 * SVT];

    const size_t rowstr = H_ * D_;
    const size_t base = ((size_t)b * L_ + (size_t)c * T_) * rowstr + (size_t)h * D_;

    // k -> bf16 with RATIO fold (same layout, coalesced)
    for (int i = tid; i < T_ * 16; i += 256) {
        int t = i >> 4, dd = (i & 15) * 4;
        float4 kv = *(const float4*)(key + base + (size_t)t * rowstr + dd);
        uint2 o; o.x = pack2bf(kv.x * RATIO, kv.y * RATIO);
        o.y = pack2bf(kv.z * RATIO, kv.w * RATIO);
        *(uint2*)(kbf + base + (size_t)t * rowstr + dd) = o;
    }
    // V transpose -> LDS -> VTg [d][t]
    for (int i = tid; i < T_ * 16; i += 256) {
        int t = i >> 4, d4 = (i & 15) * 4;
        float4 vv = *(const float4*)(val + base + (size_t)t * rowstr + d4);
        VT[(d4 + 0) * SVT + t] = f2bf(vv.x);
        VT[(d4 + 1) * SVT + t] = f2bf(vv.y);
        VT[(d4 + 2) * SVT + t] = f2bf(vv.z);
        VT[(d4 + 3) * SVT + t] = f2bf(vv.w);
    }
    __syncthreads();
    unsigned short* vout = VTg + ((size_t)bh * C_ + c) * (D_ * T_);
    for (int i = tid; i < D_ * 16; i += 256) {
        int d = i >> 4, tt = (i & 15) * 8;
        *(uint4*)(vout + d * T_ + tt) = *(const uint4*)&VT[d * SVT + tt];
    }
    // proj -> bf16 (c==0 blocks: 16 x 256 threads x 1 float4 = all 16384)
    if (c == 0) {
        int i = bh * 256 + tid;
        float4 pv = *(const float4*)(proj + (size_t)i * 4);
        uint2 o; o.x = pack2bf(pv.x, pv.y); o.y = pack2bf(pv.z, pv.w);
        *(uint2*)(Pbf + (size_t)i * 4) = o;
    }
}

// ---------------- scan: fused phase1+phase2 ----------------
// Block (mq, bh, dh): m-slice 32 (mq*32..), d-slice 32 (dh*32..). 4 waves:
// wave w = (dt = w&1, ct2 = w>>1) owns S-tile rows d = dh*32+dt*16,
// cols m = mq*32+ct2*16. Running S-prefix in acc (floatx4). For Kp, wave w
// owns t-rows 32w..32w+31 of the chunk. One barrier per chunk (2-buf KpT).
__global__ __launch_bounds__(256, 2)
void scan_kernel(const unsigned short* __restrict__ kbf,
                 const unsigned short* __restrict__ VTg,
                 const unsigned short* __restrict__ Pbf,
                 unsigned short* __restrict__ S, float* __restrict__ Z) {
    const int mq = blockIdx.x, bh = blockIdx.y, dh = blockIdx.z;
    const int b = bh / H_, h = bh % H_;
    const int tid = threadIdx.x;
    const int w = tid >> 6, lane = tid & 63;
    const int l15 = lane & 15, quad = lane >> 4;
    const int dt = w & 1, ct2 = w >> 1;

    __shared__ __align__(16) unsigned short KpT[2][32 * SVT];  // [m][t] 2-buf
    __shared__ float zP[2][4][32];

    const size_t rowstr = H_ * D_;

    // persistent P B-frags for this m-slice
    short8 pf[2][2];
#pragma unroll
    for (int ct = 0; ct < 2; ++ct)
#pragma unroll
        for (int kk = 0; kk < 2; ++kk)
            pf[ct][kk] = *(const short8*)(Pbf + (size_t)(mq * 32 + ct * 16 + l15) * D_
                                          + kk * 32 + quad * 8);

    floatx4 acc = {0.f, 0.f, 0.f, 0.f};   // running S-prefix (fp32)
    float zreg = 0.f;                      // running z-prefix (wave0 lanes 0..31)

    // preload chunk 0 K A-frags
    short8 kf[2][2];
#pragma unroll
    for (int rt = 0; rt < 2; ++rt)
#pragma unroll
        for (int kk = 0; kk < 2; ++kk)
            kf[rt][kk] = *(const short8*)(kbf + ((size_t)b * L_) * rowstr + (size_t)h * D_
                                          + (size_t)(32 * w + rt * 16 + l15) * rowstr
                                          + kk * 32 + quad * 8);

    const int vrow = dh * 32 + dt * 16 + l15;
    const int drow0 = dh * 32 + dt * 16 + quad * 4;
    const int mcol = mq * 32 + ct2 * 16 + l15;

    for (int c = 0; c < C_; ++c) {
        const int buf = c & 1;
        // Kp for own t-rows -> KpT[buf] + z partials
        float zpart[2] = {0.f, 0.f};
#pragma unroll
        for (int rt = 0; rt < 2; ++rt)
#pragma unroll
            for (int ct = 0; ct < 2; ++ct) {
                floatx4 a = {0.f, 0.f, 0.f, 0.f};
                a = MFMA16(kf[rt][0], pf[ct][0], a);
                a = MFMA16(kf[rt][1], pf[ct][1], a);
                float k0 = fmaxf(a[0], 0.f) + STAB;
                float k1 = fmaxf(a[1], 0.f) + STAB;
                float k2 = fmaxf(a[2], 0.f) + STAB;
                float k3 = fmaxf(a[3], 0.f) + STAB;
                zpart[ct] += (k0 + k1) + (k2 + k3);
                uint2 pk; pk.x = pack2bf(k0, k1); pk.y = pack2bf(k2, k3);
                *(uint2*)&KpT[buf][(ct * 16 + l15) * SVT + 32 * w + rt * 16 + quad * 4] = pk;
            }
#pragma unroll
        for (int ct = 0; ct < 2; ++ct) {
            float z = zpart[ct];
            z += __shfl_xor(z, 16, 64);
            z += __shfl_xor(z, 32, 64);
            if (quad == 0) zP[buf][w][ct * 16 + l15] = z;
        }
        // prefetch next chunk's K frags (in-flight across the barrier)
        if (c + 1 < C_) {
            const size_t kb2 = ((size_t)b * L_ + (size_t)(c + 1) * T_) * rowstr + (size_t)h * D_;
#pragma unroll
            for (int rt = 0; rt < 2; ++rt)
#pragma unroll
                for (int kk = 0; kk < 2; ++kk)
                    kf[rt][kk] = *(const short8*)(kbf + kb2
                                                  + (size_t)(32 * w + rt * 16 + l15) * rowstr
                                                  + kk * 32 + quad * 8);
        }
        // V^T A-frags for this chunk
        const unsigned short* vbase = VTg + ((size_t)bh * C_ + c) * (D_ * T_);
        short8 vf[4];
#pragma unroll
        for (int k4 = 0; k4 < 4; ++k4)
            vf[k4] = *(const short8*)(vbase + (size_t)vrow * T_ + k4 * 32 + quad * 8);

        __syncthreads();   // KpT[buf] + zP[buf] complete

        // store EXCLUSIVE prefix (acc excludes chunk c)
        unsigned short* Sp = S + ((size_t)bh * C_ + c) * (M_ * D_);
#pragma unroll
        for (int r = 0; r < 4; ++r)
            Sp[(size_t)(drow0 + r) * M_ + mcol] = f2bf(acc[r]);
        if (dh == 0 && w == 0 && lane < 32) {
            float zs = zP[buf][0][lane] + zP[buf][1][lane]
                     + zP[buf][2][lane] + zP[buf][3][lane];
            Z[((size_t)bh * C_ + c) * M_ + mq * 32 + lane] = zreg;
            zreg += zs;
        }
        // accumulate chunk c into running S
#pragma unroll
        for (int k4 = 0; k4 < 4; ++k4) {
            short8 kb = *(const short8*)&KpT[buf][(ct2 * 16 + l15) * SVT + k4 * 32 + quad * 8];
            acc = MFMA16(vf[k4], kb, acc);
        }
    }
}

// ---------------- Phase 3: per-chunk output via MFMA (R6 structure) -------
// 512 thr / 8 waves; wave w owns output rows 16w..16w+15. m in two halves:
// fg{0,1} -> KpL half -> A += Qp.Kp^T, barrier, fg{2,3} -> second half.
// Am overlays KpL after the final A barrier. P/K/V frags from Pbf/kbf/VTg.
__global__ __launch_bounds__(512, 2)
void phase3_kernel(const float* __restrict__ q,
                   const unsigned short* __restrict__ kbf,
                   const unsigned short* __restrict__ VTg,
                   const unsigned short* __restrict__ Pbf,
                   const unsigned short* __restrict__ S, const float* __restrict__ Z,
                   float* __restrict__ out) {
    const int c = blockIdx.x, bh = blockIdx.y;
    const int b = bh / H_, h = bh % H_;
    const int tid = threadIdx.x;
    const int w = tid >> 6, lane = tid & 63;
    const int l15 = lane & 15, quad = lane >> 4;

    __shared__ __align__(16) unsigned short KpL[T_ * SVT];     // [t][mloc]; Am overlays
    __shared__ __align__(16) unsigned short QpS[8 * 16 * SQS]; // per-wave stage

    const size_t rowstr = H_ * D_;
    const size_t base = ((size_t)b * L_ + (size_t)c * T_) * rowstr + (size_t)h * D_;
    const unsigned short* Sp = S + (size_t)(bh * C_ + c) * (M_ * D_);
    const float* Zp = Z + (size_t)(bh * C_ + c) * M_;
    const unsigned short* Vc = VTg + ((size_t)bh * C_ + c) * (D_ * T_);

    short8 qf[2], kf[2];
#pragma unroll
    for (int kk = 0; kk < 2; ++kk) {
        size_t ro = base + (size_t)(16 * w + l15) * rowstr + kk * 32 + quad * 8;
        qf[kk] = ldg8_bfs(q + ro);                 // RATIO folded (exact)
        kf[kk] = *(const short8*)(kbf + ro);       // pre-folded in prep
    }

    unsigned short* myQp = QpS + w * 16 * SQS;
    floatx4 num[4];
    floatx4 Aacc[8];
#pragma unroll
    for (int dt = 0; dt < 4; ++dt) { floatx4 z4 = {0.f,0.f,0.f,0.f}; num[dt] = z4; }
#pragma unroll
    for (int ct = 0; ct < 8; ++ct) { floatx4 z4 = {0.f,0.f,0.f,0.f}; Aacc[ct] = z4; }
    float dz[4] = {0.f, 0.f, 0.f, 0.f};

    for (int hh = 0; hh < 2; ++hh) {
        short8 qa[4];
#pragma unroll
        for (int fgl = 0; fgl < 2; ++fgl) {
            const int fg = 2 * hh + fgl;
#pragma unroll
            for (int ct = 0; ct < 4; ++ct) {
                const unsigned short* pp = Pbf + (size_t)(fg * 64 + ct * 16 + l15) * D_;
                short8 pf0 = *(const short8*)(pp + quad * 8);
                short8 pf1 = *(const short8*)(pp + 32 + quad * 8);
                floatx4 aq = {0.f, 0.f, 0.f, 0.f};
                aq = MFMA16(qf[0], pf0, aq);
                aq = MFMA16(qf[1], pf1, aq);
                floatx4 ak = {0.f, 0.f, 0.f, 0.f};
                ak = MFMA16(kf[0], pf0, ak);
                ak = MFMA16(kf[1], pf1, ak);
                const int mloc = fgl * 64 + ct * 16 + l15;
                float zv = Zp[hh * 128 + mloc];
#pragma unroll
                for (int r = 0; r < 4; ++r) {
                    float qpv = fmaxf(aq[r], 0.f) + STAB;
                    float kpv = fmaxf(ak[r], 0.f) + STAB;
                    myQp[(quad * 4 + r) * SQS + ct * 16 + l15] = f2bf(qpv);
                    KpL[(size_t)(16 * w + quad * 4 + r) * SVT + mloc] = f2bf(kpv);
                    dz[r] = fmaf(qpv, zv, dz[r]);
                }
            }
            // read back own-wave A-frags (same-wave LDS dep; no barrier)
#pragma unroll
            for (int kk = 0; kk < 2; ++kk)
                qa[fgl * 2 + kk] = *(const short8*)&myQp[l15 * SQS + kk * 32 + quad * 8];
        }
        // num += Qp . S_prefix (this m-half)
#pragma unroll
        for (int dt = 0; dt < 4; ++dt)
#pragma unroll
            for (int kc = 0; kc < 4; ++kc) {
                short8 sb = *(const short8*)(Sp + (size_t)(dt * 16 + l15) * M_
                                             + hh * 128 + kc * 32 + quad * 8);
                num[dt] = MFMA16(qa[kc], sb, num[dt]);
            }
        __syncthreads();   // KpL half complete
        // A += Qp.Kp^T over this half; causal tile-skip (wave-uniform)
#pragma unroll
        for (int ct = 0; ct < 8; ++ct) {
            if (ct <= w) {
#pragma unroll
                for (int kc = 0; kc < 4; ++kc) {
                    short8 kb = *(const short8*)&KpL[(size_t)(ct * 16 + l15) * SVT
                                                     + kc * 32 + quad * 8];
                    Aacc[ct] = MFMA16(qa[kc], kb, Aacc[ct]);
                }
            }
        }
        __syncthreads();   // A reads done (next half / Am overlay may write)
    }
#pragma unroll
    for (int r = 0; r < 4; ++r) {
        dz[r] += __shfl_xor(dz[r], 1, 64);
        dz[r] += __shfl_xor(dz[r], 2, 64);
        dz[r] += __shfl_xor(dz[r], 4, 64);
        dz[r] += __shfl_xor(dz[r], 8, 64);
    }

    // mask (exact on diagonal tile), row-sum denA, write Am (own rows, KpL overlay)
    unsigned short* AmL = KpL;
    float da[4] = {0.f, 0.f, 0.f, 0.f};
#pragma unroll
    for (int ct = 0; ct < 8; ++ct)
#pragma unroll
        for (int r = 0; r < 4; ++r) {
            float av = Aacc[ct][r];
            if (ct > w || (ct == w && l15 > quad * 4 + r)) av = 0.f;
            AmL[(size_t)(16 * w + quad * 4 + r) * SVT + ct * 16 + l15] = f2bf(av);
            da[r] += av;
        }
#pragma unroll
    for (int r = 0; r < 4; ++r) {
        da[r] += __shfl_xor(da[r], 1, 64);
        da[r] += __shfl_xor(da[r], 2, 64);
        da[r] += __shfl_xor(da[r], 4, 64);
        da[r] += __shfl_xor(da[r], 8, 64);
    }

    // num += A_masked . V  (own rows; V B-frags straight from VTg)
    for (int k4 = 0; k4 <= (w >> 1); ++k4) {
        short8 am = *(const short8*)&AmL[(size_t)(16 * w + l15) * SVT
                                         + k4 * 32 + quad * 8];
#pragma unroll
        for (int dt = 0; dt < 4; ++dt) {
            short8 vb = *(const short8*)(Vc + (size_t)(dt * 16 + l15) * T_
                                         + k4 * 32 + quad * 8);
            num[dt] = MFMA16(am, vb, num[dt]);
        }
    }

    // epilogue
#pragma unroll
    for (int r = 0; r < 4; ++r) {
        float den = da[r] + dz[r];
        if (den <= 0.f) den = 1.f;
        float inv = 1.f / den;
        int t = 16 * w + quad * 4 + r;
#pragma unroll
        for (int dt = 0; dt < 4; ++dt)
            out[base + (size_t)t * rowstr + dt * 16 + l15] = num[dt][r] * inv;
    }
}

extern "C" void kernel_launch(void* const* d_in, const int* in_sizes, int n_in,
                              void* d_out, int out_size, void* d_ws, size_t ws_size,
                              hipStream_t stream) {
    const float* q    = (const float*)d_in[0];
    const float* k    = (const float*)d_in[1];
    const float* v    = (const float*)d_in[2];
    const float* proj = (const float*)d_in[3];
    float* out = (float*)d_out;

    const size_t nS = (size_t)NBH * C_ * D_ * M_;   // shorts
    const size_t nZ = (size_t)NBH * C_ * M_;        // floats
    const size_t nK = (size_t)B_ * L_ * H_ * D_;    // shorts (kbf)
    const size_t nV = (size_t)NBH * C_ * D_ * T_;   // shorts (VTg)
    unsigned short* S   = (unsigned short*)d_ws;
    float*          Z   = (float*)(S + nS);
    unsigned short* kbf = (unsigned short*)(Z + nZ);
    unsigned short* VTg = kbf + nK;
    unsigned short* Pbf = VTg + nV;

    prep_kernel<<<dim3(C_, NBH), dim3(256), 0, stream>>>(k, v, proj, kbf, VTg, Pbf);
    scan_kernel<<<dim3(8, NBH, 2), dim3(256), 0, stream>>>(kbf, VTg, Pbf, S, Z);
    phase3_kernel<<<dim3(C_, NBH), dim3(512), 0, stream>>>(q, kbf, VTg, Pbf, S, Z, out);
}

// Round 9
// 184.045 us; speedup vs baseline: 1.0658x; 1.0658x over previous
//
#include <hip/hip_runtime.h>
#include <hip/hip_bf16.h>

// Causal linear attention (Performer ReLU kernel) via chunked MFMA (bf16).
// B=2 L=4096 H=8 D=64 M=256 fp32 in/out. Chunk T=128, C=32, NBH=16.
// R9: prep-lite (VTg+Pbf only; K converted in-kernel via ldg8_bfs).
//     scan: producer/consumer wave specialization (8 waves: 0-3 produce
//     Kp(c+1) into spare buffer WHILE 4-7 consume Kp(c)); 1 barrier/chunk;
//     running S-prefix in MFMA accumulators (exclusive store-then-add).
//     phase3: R8 structure, kf from fp32 K.
// C/D layout (m89): col = lane&15, row = quad*4 + reg.
// ws: S bf16 16.8M | Z fp32 0.5M | VTg bf16 8.4M | Pbf 32K ~= 25.7 MB.

#define B_   2
#define L_   4096
#define H_   8
#define D_   64
#define M_   256
#define T_   128
#define C_   (L_ / T_)   // 32
#define NBH  (B_ * H_)   // 16
#define RATIO 0.0625f    // 1/sqrt(256) == 2^-4, exact fold into k/q staging
#define STAB  0.001f
#define SVT  136         // KpL/Am/KpT row stride (272B, 16B-aligned)
#define SQS  72          // Qp stage row stride

typedef __attribute__((ext_vector_type(8))) short short8;
typedef __attribute__((ext_vector_type(4))) float floatx4;

#define MFMA16(a, b, c) __builtin_amdgcn_mfma_f32_16x16x32_bf16(a, b, c, 0, 0, 0)

__device__ inline unsigned short f2bf(float x) {
    union { float f; unsigned u; } v; v.f = x;
    unsigned r = v.u + 0x7FFF + ((v.u >> 16) & 1);
    return (unsigned short)(r >> 16);
}
__device__ inline unsigned pack2bf(float a, float b) {
    __hip_bfloat162 h = __float22bfloat162_rn(make_float2(a, b));
    unsigned u; __builtin_memcpy(&u, &h, 4);
    return u;
}
// fp32 -> bf16 frag load with RATIO pre-fold (exact: 2^-4 is exponent-only)
__device__ inline short8 ldg8_bfs(const float* p) {
    float4 a = *(const float4*)p;
    float4 b = *(const float4*)(p + 4);
    short8 r;
    r[0] = (short)f2bf(a.x * RATIO); r[1] = (short)f2bf(a.y * RATIO);
    r[2] = (short)f2bf(a.z * RATIO); r[3] = (short)f2bf(a.w * RATIO);
    r[4] = (short)f2bf(b.x * RATIO); r[5] = (short)f2bf(b.y * RATIO);
    r[6] = (short)f2bf(b.z * RATIO); r[7] = (short)f2bf(b.w * RATIO);
    return r;
}

// ---------------- prep-lite: VTg (V^T bf16 [bh][c][d][t]) + Pbf ----------
__global__ __launch_bounds__(256, 2)
void prep_kernel(const float* __restrict__ val, const float* __restrict__ proj,
                 unsigned short* __restrict__ VTg, unsigned short* __restrict__ Pbf) {
    const int c = blockIdx.x, bh = blockIdx.y;
    const int b = bh / H_, h = bh % H_;
    const int tid = threadIdx.x;
    __shared__ __align__(16) unsigned short VT[64 * SVT];

    const size_t rowstr = H_ * D_;
    const size_t base = ((size_t)b * L_ + (size_t)c * T_) * rowstr + (size_t)h * D_;

    for (int i = tid; i < T_ * 16; i += 256) {
        int t = i >> 4, d4 = (i & 15) * 4;
        float4 vv = *(const float4*)(val + base + (size_t)t * rowstr + d4);
        VT[(d4 + 0) * SVT + t] = f2bf(vv.x);
        VT[(d4 + 1) * SVT + t] = f2bf(vv.y);
        VT[(d4 + 2) * SVT + t] = f2bf(vv.z);
        VT[(d4 + 3) * SVT + t] = f2bf(vv.w);
    }
    __syncthreads();
    unsigned short* vout = VTg + ((size_t)bh * C_ + c) * (D_ * T_);
    for (int i = tid; i < D_ * 16; i += 256) {
        int d = i >> 4, tt = (i & 15) * 8;
        *(uint4*)(vout + d * T_ + tt) = *(const uint4*)&VT[d * SVT + tt];
    }
    if (c == 0) {
        int i = bh * 256 + tid;
        float4 pv = *(const float4*)(proj + (size_t)i * 4);
        uint2 o; o.x = pack2bf(pv.x, pv.y); o.y = pack2bf(pv.z, pv.w);
        *(uint2*)(Pbf + (size_t)i * 4) = o;
    }
}

// ---------------- scan: fused phase1+2, producer/consumer waves ----------
// Block (mq 8, bh 16, dh 2), 512 thr / 8 waves. Producers (w 0-3): Kp for
// t-rows 32w..+31 x m-slice 32 of chunk c+1 -> KpT[buf^1]. Consumers
// (w 4-7, dt=w&1, ct2=(w>>1)&1): S-tile rows d=dh*32+dt*16, cols
// m=mq*32+ct2*16; store EXCLUSIVE prefix then acc += V^T(c).Kp(c).
// One barrier per chunk; S-prefix fp32 in accumulators.
__global__ __launch_bounds__(512, 1)
void scan_kernel(const float* __restrict__ key,
                 const unsigned short* __restrict__ VTg,
                 const unsigned short* __restrict__ Pbf,
                 unsigned short* __restrict__ S, float* __restrict__ Z) {
    const int mq = blockIdx.x, bh = blockIdx.y, dh = blockIdx.z;
    const int b = bh / H_, h = bh % H_;
    const int tid = threadIdx.x;
    const int w = tid >> 6, lane = tid & 63;
    const int l15 = lane & 15, quad = lane >> 4;

    __shared__ __align__(16) unsigned short KpT[2][32 * SVT];  // [m][t] 2-buf
    __shared__ float zP[2][4][32];

    const size_t rowstr = H_ * D_;
    const size_t khead = (size_t)b * L_ * rowstr + (size_t)h * D_;

    if (w < 4) {
        // ---------------- producer ----------------
        short8 pf[2][2];
#pragma unroll
        for (int ct = 0; ct < 2; ++ct)
#pragma unroll
            for (int kk = 0; kk < 2; ++kk)
                pf[ct][kk] = *(const short8*)(Pbf + (size_t)(mq * 32 + ct * 16 + l15) * D_
                                              + kk * 32 + quad * 8);
        short8 kf[2][2];
#pragma unroll
        for (int rt = 0; rt < 2; ++rt)
#pragma unroll
            for (int kk = 0; kk < 2; ++kk)
                kf[rt][kk] = ldg8_bfs(key + khead
                                      + (size_t)(32 * w + rt * 16 + l15) * rowstr
                                      + kk * 32 + quad * 8);
        // produce chunk 0 -> buf 0
#pragma unroll
        for (int ct = 0; ct < 2; ++ct) {
            float zpart = 0.f;
#pragma unroll
            for (int rt = 0; rt < 2; ++rt) {
                floatx4 a = {0.f, 0.f, 0.f, 0.f};
                a = MFMA16(kf[rt][0], pf[ct][0], a);
                a = MFMA16(kf[rt][1], pf[ct][1], a);
                float k0 = fmaxf(a[0], 0.f) + STAB;
                float k1 = fmaxf(a[1], 0.f) + STAB;
                float k2 = fmaxf(a[2], 0.f) + STAB;
                float k3 = fmaxf(a[3], 0.f) + STAB;
                zpart += (k0 + k1) + (k2 + k3);
                uint2 pk; pk.x = pack2bf(k0, k1); pk.y = pack2bf(k2, k3);
                *(uint2*)&KpT[0][(ct * 16 + l15) * SVT + 32 * w + rt * 16 + quad * 4] = pk;
            }
            zpart += __shfl_xor(zpart, 16, 64);
            zpart += __shfl_xor(zpart, 32, 64);
            if (quad == 0) zP[0][w][ct * 16 + l15] = zpart;
        }
        // prefetch chunk 1
#pragma unroll
        for (int rt = 0; rt < 2; ++rt)
#pragma unroll
            for (int kk = 0; kk < 2; ++kk)
                kf[rt][kk] = ldg8_bfs(key + khead + (size_t)T_ * rowstr
                                      + (size_t)(32 * w + rt * 16 + l15) * rowstr
                                      + kk * 32 + quad * 8);
        __syncthreads();
        for (int c = 0; c < C_; ++c) {
            const int buf = c & 1;
            if (c + 1 < C_) {
#pragma unroll
                for (int ct = 0; ct < 2; ++ct) {
                    float zpart = 0.f;
#pragma unroll
                    for (int rt = 0; rt < 2; ++rt) {
                        floatx4 a = {0.f, 0.f, 0.f, 0.f};
                        a = MFMA16(kf[rt][0], pf[ct][0], a);
                        a = MFMA16(kf[rt][1], pf[ct][1], a);
                        float k0 = fmaxf(a[0], 0.f) + STAB;
                        float k1 = fmaxf(a[1], 0.f) + STAB;
                        float k2 = fmaxf(a[2], 0.f) + STAB;
                        float k3 = fmaxf(a[3], 0.f) + STAB;
                        zpart += (k0 + k1) + (k2 + k3);
                        uint2 pk; pk.x = pack2bf(k0, k1); pk.y = pack2bf(k2, k3);
                        *(uint2*)&KpT[buf ^ 1][(ct * 16 + l15) * SVT
                                               + 32 * w + rt * 16 + quad * 4] = pk;
                    }
                    zpart += __shfl_xor(zpart, 16, 64);
                    zpart += __shfl_xor(zpart, 32, 64);
                    if (quad == 0) zP[buf ^ 1][w][ct * 16 + l15] = zpart;
                }
                if (c + 2 < C_) {
                    const size_t kb2 = khead + (size_t)(c + 2) * T_ * rowstr;
#pragma unroll
                    for (int rt = 0; rt < 2; ++rt)
#pragma unroll
                        for (int kk = 0; kk < 2; ++kk)
                            kf[rt][kk] = ldg8_bfs(key + kb2
                                                  + (size_t)(32 * w + rt * 16 + l15) * rowstr
                                                  + kk * 32 + quad * 8);
                }
            }
            __syncthreads();
        }
    } else {
        // ---------------- consumer ----------------
        const int w4 = w - 4;
        const int dt = w4 & 1, ct2 = w4 >> 1;
        const int vrow = dh * 32 + dt * 16 + l15;
        const int drow0 = dh * 32 + dt * 16 + quad * 4;
        const int mcol = mq * 32 + ct2 * 16 + l15;
        const unsigned short* vhead = VTg + (size_t)bh * C_ * (D_ * T_);

        floatx4 acc = {0.f, 0.f, 0.f, 0.f};
        float zreg = 0.f;
        short8 vf[4];
#pragma unroll
        for (int k4 = 0; k4 < 4; ++k4)
            vf[k4] = *(const short8*)(vhead + (size_t)vrow * T_ + k4 * 32 + quad * 8);
        __syncthreads();
        for (int c = 0; c < C_; ++c) {
            const int buf = c & 1;
            // exclusive prefix store (acc excludes chunk c)
            unsigned short* Sp = S + ((size_t)bh * C_ + c) * (M_ * D_);
#pragma unroll
            for (int r = 0; r < 4; ++r)
                Sp[(size_t)(drow0 + r) * M_ + mcol] = f2bf(acc[r]);
            if (w == 4 && dh == 0 && lane < 32) {
                float zs = zP[buf][0][lane] + zP[buf][1][lane]
                         + zP[buf][2][lane] + zP[buf][3][lane];
                Z[((size_t)bh * C_ + c) * M_ + mq * 32 + lane] = zreg;
                zreg += zs;
            }
            // prefetch next chunk V frags (independent of MFMAs below)
            short8 vn[4];
            if (c + 1 < C_) {
                const unsigned short* vb2 = vhead + (size_t)(c + 1) * (D_ * T_);
#pragma unroll
                for (int k4 = 0; k4 < 4; ++k4)
                    vn[k4] = *(const short8*)(vb2 + (size_t)vrow * T_ + k4 * 32 + quad * 8);
            }
            // acc += V^T(c) . Kp(c)
#pragma unroll
            for (int k4 = 0; k4 < 4; ++k4) {
                short8 kb = *(const short8*)&KpT[buf][(ct2 * 16 + l15) * SVT
                                                      + k4 * 32 + quad * 8];
                acc = MFMA16(vf[k4], kb, acc);
            }
            if (c + 1 < C_) {
#pragma unroll
                for (int k4 = 0; k4 < 4; ++k4) vf[k4] = vn[k4];
            }
            __syncthreads();
        }
    }
}

// ---------------- Phase 3: per-chunk output via MFMA (R8 structure) -------
// 512 thr / 8 waves; wave w owns output rows 16w..16w+15. m in two halves:
// fg{0,1} -> KpL half -> A += Qp.Kp^T, barrier, fg{2,3} -> second half.
// Am overlays KpL after the final A barrier. P/V frags from Pbf/VTg; q/k
// converted in-flight (ldg8_bfs, RATIO folded).
__global__ __launch_bounds__(512, 2)
void phase3_kernel(const float* __restrict__ q, const float* __restrict__ key,
                   const unsigned short* __restrict__ VTg,
                   const unsigned short* __restrict__ Pbf,
                   const unsigned short* __restrict__ S, const float* __restrict__ Z,
                   float* __restrict__ out) {
    const int c = blockIdx.x, bh = blockIdx.y;
    const int b = bh / H_, h = bh % H_;
    const int tid = threadIdx.x;
    const int w = tid >> 6, lane = tid & 63;
    const int l15 = lane & 15, quad = lane >> 4;

    __shared__ __align__(16) unsigned short KpL[T_ * SVT];     // [t][mloc]; Am overlays
    __shared__ __align__(16) unsigned short QpS[8 * 16 * SQS]; // per-wave stage

    const size_t rowstr = H_ * D_;
    const size_t base = ((size_t)b * L_ + (size_t)c * T_) * rowstr + (size_t)h * D_;
    const unsigned short* Sp = S + (size_t)(bh * C_ + c) * (M_ * D_);
    const float* Zp = Z + (size_t)(bh * C_ + c) * M_;
    const unsigned short* Vc = VTg + ((size_t)bh * C_ + c) * (D_ * T_);

    short8 qf[2], kf[2];
#pragma unroll
    for (int kk = 0; kk < 2; ++kk) {
        size_t ro = base + (size_t)(16 * w + l15) * rowstr + kk * 32 + quad * 8;
        qf[kk] = ldg8_bfs(q + ro);
        kf[kk] = ldg8_bfs(key + ro);
    }

    unsigned short* myQp = QpS + w * 16 * SQS;
    floatx4 num[4];
    floatx4 Aacc[8];
#pragma unroll
    for (int dt = 0; dt < 4; ++dt) { floatx4 z4 = {0.f,0.f,0.f,0.f}; num[dt] = z4; }
#pragma unroll
    for (int ct = 0; ct < 8; ++ct) { floatx4 z4 = {0.f,0.f,0.f,0.f}; Aacc[ct] = z4; }
    float dz[4] = {0.f, 0.f, 0.f, 0.f};

    for (int hh = 0; hh < 2; ++hh) {
        short8 qa[4];
#pragma unroll
        for (int fgl = 0; fgl < 2; ++fgl) {
            const int fg = 2 * hh + fgl;
#pragma unroll
            for (int ct = 0; ct < 4; ++ct) {
                const unsigned short* pp = Pbf + (size_t)(fg * 64 + ct * 16 + l15) * D_;
                short8 pf0 = *(const short8*)(pp + quad * 8);
                short8 pf1 = *(const short8*)(pp + 32 + quad * 8);
                floatx4 aq = {0.f, 0.f, 0.f, 0.f};
                aq = MFMA16(qf[0], pf0, aq);
                aq = MFMA16(qf[1], pf1, aq);
                floatx4 ak = {0.f, 0.f, 0.f, 0.f};
                ak = MFMA16(kf[0], pf0, ak);
                ak = MFMA16(kf[1], pf1, ak);
                const int mloc = fgl * 64 + ct * 16 + l15;
                float zv = Zp[hh * 128 + mloc];
#pragma unroll
                for (int r = 0; r < 4; ++r) {
                    float qpv = fmaxf(aq[r], 0.f) + STAB;
                    float kpv = fmaxf(ak[r], 0.f) + STAB;
                    myQp[(quad * 4 + r) * SQS + ct * 16 + l15] = f2bf(qpv);
                    KpL[(size_t)(16 * w + quad * 4 + r) * SVT + mloc] = f2bf(kpv);
                    dz[r] = fmaf(qpv, zv, dz[r]);
                }
            }
            // read back own-wave A-frags (same-wave LDS dep; no barrier)
#pragma unroll
            for (int kk = 0; kk < 2; ++kk)
                qa[fgl * 2 + kk] = *(const short8*)&myQp[l15 * SQS + kk * 32 + quad * 8];
        }
        // num += Qp . S_prefix (this m-half)
#pragma unroll
        for (int dt = 0; dt < 4; ++dt)
#pragma unroll
            for (int kc = 0; kc < 4; ++kc) {
                short8 sb = *(const short8*)(Sp + (size_t)(dt * 16 + l15) * M_
                                             + hh * 128 + kc * 32 + quad * 8);
                num[dt] = MFMA16(qa[kc], sb, num[dt]);
            }
        __syncthreads();   // KpL half complete
        // A += Qp.Kp^T over this half; causal tile-skip (wave-uniform)
#pragma unroll
        for (int ct = 0; ct < 8; ++ct) {
            if (ct <= w) {
#pragma unroll
                for (int kc = 0; kc < 4; ++kc) {
                    short8 kb = *(const short8*)&KpL[(size_t)(ct * 16 + l15) * SVT
                                                     + kc * 32 + quad * 8];
                    Aacc[ct] = MFMA16(qa[kc], kb, Aacc[ct]);
                }
            }
        }
        __syncthreads();   // A reads done (next half / Am overlay may write)
    }
#pragma unroll
    for (int r = 0; r < 4; ++r) {
        dz[r] += __shfl_xor(dz[r], 1, 64);
        dz[r] += __shfl_xor(dz[r], 2, 64);
        dz[r] += __shfl_xor(dz[r], 4, 64);
        dz[r] += __shfl_xor(dz[r], 8, 64);
    }

    // mask (exact on diagonal tile), row-sum denA, write Am (own rows, KpL overlay)
    unsigned short* AmL = KpL;
    float da[4] = {0.f, 0.f, 0.f, 0.f};
#pragma unroll
    for (int ct = 0; ct < 8; ++ct)
#pragma unroll
        for (int r = 0; r < 4; ++r) {
            float av = Aacc[ct][r];
            if (ct > w || (ct == w && l15 > quad * 4 + r)) av = 0.f;
            AmL[(size_t)(16 * w + quad * 4 + r) * SVT + ct * 16 + l15] = f2bf(av);
            da[r] += av;
        }
#pragma unroll
    for (int r = 0; r < 4; ++r) {
        da[r] += __shfl_xor(da[r], 1, 64);
        da[r] += __shfl_xor(da[r], 2, 64);
        da[r] += __shfl_xor(da[r], 4, 64);
        da[r] += __shfl_xor(da[r], 8, 64);
    }

    // num += A_masked . V  (own rows; V B-frags straight from VTg)
    for (int k4 = 0; k4 <= (w >> 1); ++k4) {
        short8 am = *(const short8*)&AmL[(size_t)(16 * w + l15) * SVT
                                         + k4 * 32 + quad * 8];
#pragma unroll
        for (int dt = 0; dt < 4; ++dt) {
            short8 vb = *(const short8*)(Vc + (size_t)(dt * 16 + l15) * T_
                                         + k4 * 32 + quad * 8);
            num[dt] = MFMA16(am, vb, num[dt]);
        }
    }

    // epilogue
#pragma unroll
    for (int r = 0; r < 4; ++r) {
        float den = da[r] + dz[r];
        if (den <= 0.f) den = 1.f;
        float inv = 1.f / den;
        int t = 16 * w + quad * 4 + r;
#pragma unroll
        for (int dt = 0; dt < 4; ++dt)
            out[base + (size_t)t * rowstr + dt * 16 + l15] = num[dt][r] * inv;
    }
}

extern "C" void kernel_launch(void* const* d_in, const int* in_sizes, int n_in,
                              void* d_out, int out_size, void* d_ws, size_t ws_size,
                              hipStream_t stream) {
    const float* q    = (const float*)d_in[0];
    const float* k    = (const float*)d_in[1];
    const float* v    = (const float*)d_in[2];
    const float* proj = (const float*)d_in[3];
    float* out = (float*)d_out;

    const size_t nS = (size_t)NBH * C_ * D_ * M_;   // shorts
    const size_t nZ = (size_t)NBH * C_ * M_;        // floats
    const size_t nV = (size_t)NBH * C_ * D_ * T_;   // shorts (VTg)
    unsigned short* S   = (unsigned short*)d_ws;
    float*          Z   = (float*)(S + nS);
    unsigned short* VTg = (unsigned short*)(Z + nZ);
    unsigned short* Pbf = VTg + nV;

    prep_kernel<<<dim3(C_, NBH), dim3(256), 0, stream>>>(v, proj, VTg, Pbf);
    scan_kernel<<<dim3(8, NBH, 2), dim3(512), 0, stream>>>(k, VTg, Pbf, S, Z);
    phase3_kernel<<<dim3(C_, NBH), dim3(512), 0, stream>>>(q, k, VTg, Pbf, S, Z, out);
}